// Round 3
// baseline (250.157 us; speedup 1.0000x reference)
//
#include <hip/hip_runtime.h>
#include <stdint.h>

// GeAT single-head layer, B=32 N=512 D=128 T=8.
// S_t = X @ (Qw^T a_t) + (Qb a_t);  dst = X@Kw^T+Kb
// VP  = X @ (Pw Vw)^T + Pw Vb      (Pw folded into val projection)
// att_raw[b,n,m] = S_{clamp(e,0)}[b,n,:] . dst[b,m,:] -> mask -> leaky -> softmax
// out = att @ VP + Pb
// All matmuls fp32-emulated: hi/lo bf16 split, 3x mfma_f32_16x16x32_bf16.

typedef short bf16x8 __attribute__((ext_vector_type(8)));
typedef float f32x4 __attribute__((ext_vector_type(4)));
typedef unsigned short u16;
typedef unsigned int u32;

__device__ __forceinline__ u16 f2bf(float x) {
    union { float f; u32 u; } v; v.f = x;
    u32 r = v.u + 0x7FFFu + ((v.u >> 16) & 1u);
    return (u16)(r >> 16);
}
__device__ __forceinline__ float bf2f(u16 h) {
    union { u32 u; float f; } v; v.u = ((u32)h) << 16; return v.f;
}
__device__ __forceinline__ void split_hl(float x, u16& h, u16& l) {
    h = f2bf(x);
    l = f2bf(x - bf2f(h));
}
__device__ __forceinline__ f32x4 mfma16(bf16x8 a, bf16x8 b, f32x4 c) {
    return __builtin_amdgcn_mfma_f32_16x16x32_bf16(a, b, c, 0, 0, 0);
}

// ---------------------------------------------------------------------------
// prep: WcatT (1280 x 128) hi/lo bf16 + bcat (1280) f32.
// rows [0,128): Kw (dst) | [128,256): Pw@Vw (VP) | [256,1280): (Qw^T a_t) cols
// ---------------------------------------------------------------------------
__global__ void prep_kernel(const float* __restrict__ Qw, const float* __restrict__ Qb,
                            const float* __restrict__ Kw, const float* __restrict__ Kb,
                            const float* __restrict__ Vw, const float* __restrict__ Vb,
                            const float* __restrict__ Aa, const float* __restrict__ Pw,
                            u16* __restrict__ WH, u16* __restrict__ WL,
                            float* __restrict__ bcat) {
    int gid = blockIdx.x * 256 + threadIdx.x;
    if (gid >= 1280 * 128) return;
    int j = gid >> 7, d = gid & 127;
    float v, bias = 0.f;
    if (j < 128) { v = Kw[j * 128 + d]; bias = Kb[j]; }
    else if (j < 256) {
        int jj = j - 128;
        float s = 0.f, bs = 0.f;
        for (int k = 0; k < 128; k++) {
            float p = Pw[jj * 128 + k];
            s += p * Vw[k * 128 + d];
            bs += p * Vb[k];
        }
        v = s; bias = bs;
    } else {
        int r = j - 256, t = r >> 7, jj = r & 127;
        float s = 0.f, bs = 0.f;
        for (int e = 0; e < 128; e++) {
            float av = Aa[(e * 128 + jj) * 8 + t];
            s += Qw[e * 128 + d] * av;
            bs += Qb[e] * av;
        }
        v = s; bias = bs;
    }
    u16 h, l; split_hl(v, h, l);
    WH[gid] = h; WL[gid] = l;
    if (d == 0) bcat[j] = bias;
}

// ---------------------------------------------------------------------------
// detect: int32 vs int64 edge layout (odd words of int64 small values are 0/-1)
// ---------------------------------------------------------------------------
__global__ void detect_kernel(const int* __restrict__ E, int* __restrict__ flag) {
    __shared__ int bad;
    if (threadIdx.x == 0) bad = 0;
    __syncthreads();
    int w0 = E[2 * threadIdx.x + 1];
    int w1 = E[2 * (threadIdx.x + 256) + 1];
    if (!(w0 == 0 || w0 == -1) || !(w1 == 0 || w1 == -1)) atomicOr(&bad, 1);
    __syncthreads();
    if (threadIdx.x == 0) *flag = (bad ? 0 : 1);
}

// ---------------------------------------------------------------------------
// econv: edges -> int8
// ---------------------------------------------------------------------------
__global__ void econv_kernel(const void* __restrict__ E, const int* __restrict__ flag,
                             signed char* __restrict__ E8) {
    int i = (blockIdx.x * 256 + threadIdx.x) * 4;
    char4 o;
    if (*flag) {
        const long long* p = (const long long*)E;
        o.x = (signed char)p[i]; o.y = (signed char)p[i + 1];
        o.z = (signed char)p[i + 2]; o.w = (signed char)p[i + 3];
    } else {
        const int* p = (const int*)E;
        o.x = (signed char)p[i]; o.y = (signed char)p[i + 1];
        o.z = (signed char)p[i + 2]; o.w = (signed char)p[i + 3];
    }
    *(char4*)(E8 + i) = o;
}

// ---------------------------------------------------------------------------
// gemm1 v3: 512 blocks = 256 g-tiles x 2 j-splits (10 j-tiles of 64 each).
// A (X tile) staged once -> register fragments; W double-buffered in LDS,
// one barrier per j-tile. XCD swizzle: same-g j-splits colocate per XCD.
// ---------------------------------------------------------------------------
__launch_bounds__(256, 2)
__global__ void gemm1_kernel(const float* __restrict__ X,
                             const u16* __restrict__ WH, const u16* __restrict__ WL,
                             const float* __restrict__ bcat,
                             u16* __restrict__ CH, u16* __restrict__ CL,
                             u16* __restrict__ VTH, u16* __restrict__ VTL) {
    const int id = blockIdx.x;
    const int xcd = id & 7, q5 = id >> 3;
    const int g0 = (xcd * 32 + (q5 >> 1)) * 64;
    const int jbase = (q5 & 1) * 10;
    __shared__ u16 WB[2][2][64 * 128];   // [buf][hi/lo], 64 KB total
    const int tid = threadIdx.x;
    const int wid = tid >> 6, lane = tid & 63;
    const int wr = (wid >> 1) * 32, wc = (wid & 1) * 32;
    const int lr = lane & 15, lg = lane >> 4;

    // stage A (X tile fp32 -> hi/lo) into WB[1]
    {
        const float4* Xv = (const float4*)(X + (size_t)g0 * 128);
        #pragma unroll
        for (int i = 0; i < 8; i++) {
            int idx = tid + i * 256;
            float4 x = Xv[idx];
            int row = idx >> 5, c4 = idx & 31;
            int boff = (row * 256 + c4 * 8) ^ ((row & 7) << 4);
            u16* ph = (u16*)((char*)WB[1][0] + boff);
            u16* pl = (u16*)((char*)WB[1][1] + boff);
            const float* xf = (const float*)&x;
            #pragma unroll
            for (int qq = 0; qq < 4; qq++) { u16 h, l; split_hl(xf[qq], h, l); ph[qq] = h; pl[qq] = l; }
        }
    }
    // prefetch W tile 0 into regs
    uint4 nh[4], nl[4];
    {
        const uint4* bh = (const uint4*)(WH + (size_t)(jbase + 0) * 64 * 128);
        const uint4* bl = (const uint4*)(WL + (size_t)(jbase + 0) * 64 * 128);
        #pragma unroll
        for (int i = 0; i < 4; i++) { nh[i] = bh[tid + i * 256]; nl[i] = bl[tid + i * 256]; }
    }
    __syncthreads();
    // A fragments -> registers (reused for all 10 j-tiles)
    bf16x8 afh[4][2], afl[4][2];
    #pragma unroll
    for (int ks = 0; ks < 4; ks++) {
        const int kb2 = (ks * 32 + lg * 8) * 2;
        #pragma unroll
        for (int r = 0; r < 2; r++) {
            int row = wr + r * 16 + lr;
            int boff = (row * 256 + kb2) ^ ((row & 7) << 4);
            afh[ks][r] = *(const bf16x8*)((const char*)WB[1][0] + boff);
            afl[ks][r] = *(const bf16x8*)((const char*)WB[1][1] + boff);
        }
    }
    // write W tile 0 into WB[0]  (WB[1] reads done per-thread; first overwrite
    // of WB[1] happens after the jt=0 barrier, so all waves are past reads)
    #pragma unroll
    for (int i = 0; i < 4; i++) {
        int idx = tid + i * 256;
        int row = idx >> 4, ch = idx & 15;
        int boff = (row * 256 + ch * 16) ^ ((row & 7) << 4);
        *(uint4*)((char*)WB[0][0] + boff) = nh[i];
        *(uint4*)((char*)WB[0][1] + boff) = nl[i];
    }

    for (int jt = 0; jt < 10; jt++) {
        __syncthreads();
        if (jt < 9) {                      // issue next W loads early
            const uint4* bh = (const uint4*)(WH + (size_t)(jbase + jt + 1) * 64 * 128);
            const uint4* bl = (const uint4*)(WL + (size_t)(jbase + jt + 1) * 64 * 128);
            #pragma unroll
            for (int i = 0; i < 4; i++) { nh[i] = bh[tid + i * 256]; nl[i] = bl[tid + i * 256]; }
        }
        const int cur = jt & 1;
        f32x4 acc[2][2] = {};
        #pragma unroll
        for (int ks = 0; ks < 4; ks++) {
            const int kb2 = (ks * 32 + lg * 8) * 2;
            bf16x8 bfh[2], bfl[2];
            #pragma unroll
            for (int c = 0; c < 2; c++) {
                int row = wc + c * 16 + lr;
                int boff = (row * 256 + kb2) ^ ((row & 7) << 4);
                bfh[c] = *(const bf16x8*)((const char*)WB[cur][0] + boff);
                bfl[c] = *(const bf16x8*)((const char*)WB[cur][1] + boff);
            }
            #pragma unroll
            for (int r = 0; r < 2; r++)
            #pragma unroll
            for (int c = 0; c < 2; c++) {
                acc[r][c] = mfma16(afh[ks][r], bfh[c], acc[r][c]);
                acc[r][c] = mfma16(afh[ks][r], bfl[c], acc[r][c]);
                acc[r][c] = mfma16(afl[ks][r], bfh[c], acc[r][c]);
            }
        }
        // epilogue for this j-tile
        const int j0 = (jbase + jt) * 64;
        const bool valTile = (j0 >= 128 && j0 < 256);
        #pragma unroll
        for (int r = 0; r < 2; r++)
        #pragma unroll
        for (int c = 0; c < 2; c++) {
            int j = j0 + wc + c * 16 + lr;
            float bias = bcat[j];
            #pragma unroll
            for (int qq = 0; qq < 4; qq++) {
                int g1 = g0 + wr + r * 16 + 4 * lg + qq;
                float v = acc[r][c][qq] + bias;
                u16 h, l; split_hl(v, h, l);
                if (valTile) {
                    int bb = g1 >> 9, n = g1 & 511;
                    size_t off = ((size_t)(bb * 128 + (j - 128))) * 512 + n;
                    VTH[off] = h; VTL[off] = l;
                } else {
                    size_t off = (size_t)g1 * 1280 + j;
                    CH[off] = h; CL[off] = l;
                }
            }
        }
        if (jt < 9) {                      // land prefetch into other buffer
            #pragma unroll
            for (int i = 0; i < 4; i++) {
                int idx = tid + i * 256;
                int row = idx >> 4, ch = idx & 15;
                int boff = (row * 256 + ch * 16) ^ ((row & 7) << 4);
                *(uint4*)((char*)WB[cur ^ 1][0] + boff) = nh[i];
                *(uint4*)((char*)WB[cur ^ 1][1] + boff) = nl[i];
            }
        }
    }
}

// ---------------------------------------------------------------------------
// scores: 64n x 128m tile, 512 thr / 8 waves. dst fragments register-resident
// across all 8 types; A (S_t) double-buffered with reg-staged prefetch.
// XCD-bijective swizzle: 4 m-blocks of each (n0,b) share an XCD.
// ---------------------------------------------------------------------------
__launch_bounds__(512, 2)
__global__ void scores_kernel(const u16* __restrict__ CH, const u16* __restrict__ CL,
                              const signed char* __restrict__ E8,
                              float* __restrict__ att) {
    const int id = blockIdx.x;
    const int xcd = id & 7, j = id >> 3;
    const int m0 = (j & 3) * 128;
    const int pair = xcd * 32 + (j >> 2);
    const int n0 = (pair & 7) * 64, b = pair >> 3;
    __shared__ u16 BH[128 * 128], BL[128 * 128];
    __shared__ u16 AH[2][64 * 128], AL[2][64 * 128];
    const int tid = threadIdx.x;
    const int wid = tid >> 6, lane = tid & 63;
    const int wr = (wid >> 2) * 32, wc = (wid & 3) * 32;
    const int lr = lane & 15, lg = lane >> 4;

    #pragma unroll
    for (int i = 0; i < 4; i++) {
        int idx = tid + i * 512;
        int row = idx >> 4, ch = idx & 15;
        size_t src = (size_t)(b * 512 + m0 + row) * 1280;
        int boff = (row * 256 + ch * 16) ^ ((row & 7) << 4);
        *(uint4*)((char*)BH + boff) = ((const uint4*)(CH + src))[ch];
        *(uint4*)((char*)BL + boff) = ((const uint4*)(CL + src))[ch];
    }
    int ed[2][2][4];
    #pragma unroll
    for (int r = 0; r < 2; r++)
    #pragma unroll
    for (int c = 0; c < 2; c++)
    #pragma unroll
    for (int q = 0; q < 4; q++) {
        int n = n0 + wr + r * 16 + 4 * lg + q;
        int m = m0 + wc + c * 16 + lr;
        ed[r][c][q] = E8[((size_t)b * 512 + n) * 512 + m];
    }
    uint4 rh[2], rl[2];
    {
        #pragma unroll
        for (int i = 0; i < 2; i++) {
            int idx = tid + i * 512;
            int row = idx >> 4, ch = idx & 15;
            size_t src = (size_t)(b * 512 + n0 + row) * 1280 + 256;
            rh[i] = ((const uint4*)(CH + src))[ch];
            rl[i] = ((const uint4*)(CL + src))[ch];
        }
        #pragma unroll
        for (int i = 0; i < 2; i++) {
            int idx = tid + i * 512;
            int row = idx >> 4, ch = idx & 15;
            int boff = (row * 256 + ch * 16) ^ ((row & 7) << 4);
            *(uint4*)((char*)AH[0] + boff) = rh[i];
            *(uint4*)((char*)AL[0] + boff) = rl[i];
        }
    }
    __syncthreads();
    bf16x8 bfh[4][2], bfl[4][2];
    #pragma unroll
    for (int ks = 0; ks < 4; ks++) {
        const int kb2 = (ks * 32 + lg * 8) * 2;
        #pragma unroll
        for (int c = 0; c < 2; c++) {
            int row = wc + c * 16 + lr;
            int boff = (row * 256 + kb2) ^ ((row & 7) << 4);
            bfh[ks][c] = *(const bf16x8*)((const char*)BH + boff);
            bfl[ks][c] = *(const bf16x8*)((const char*)BL + boff);
        }
    }
    float sel[2][2][4];
    #pragma unroll
    for (int r = 0; r < 2; r++)
    #pragma unroll
    for (int c = 0; c < 2; c++)
    #pragma unroll
    for (int q = 0; q < 4; q++) sel[r][c][q] = 0.f;

    for (int t = 0; t < 8; t++) {
        const int cur = t & 1;
        uint4 nh[2], nl[2];
        if (t < 7) {
            #pragma unroll
            for (int i = 0; i < 2; i++) {
                int idx = tid + i * 512;
                int row = idx >> 4, ch = idx & 15;
                size_t src = (size_t)(b * 512 + n0 + row) * 1280 + 256 + (t + 1) * 128;
                nh[i] = ((const uint4*)(CH + src))[ch];
                nl[i] = ((const uint4*)(CL + src))[ch];
            }
        }
        f32x4 acc[2][2] = {};
        #pragma unroll
        for (int ks = 0; ks < 4; ks++) {
            const int kb2 = (ks * 32 + lg * 8) * 2;
            bf16x8 afh[2], afl[2];
            #pragma unroll
            for (int r = 0; r < 2; r++) {
                int row = wr + r * 16 + lr;
                int boff = (row * 256 + kb2) ^ ((row & 7) << 4);
                afh[r] = *(const bf16x8*)((const char*)AH[cur] + boff);
                afl[r] = *(const bf16x8*)((const char*)AL[cur] + boff);
            }
            #pragma unroll
            for (int r = 0; r < 2; r++)
            #pragma unroll
            for (int c = 0; c < 2; c++) {
                acc[r][c] = mfma16(afh[r], bfh[ks][c], acc[r][c]);
                acc[r][c] = mfma16(afh[r], bfl[ks][c], acc[r][c]);
                acc[r][c] = mfma16(afl[r], bfh[ks][c], acc[r][c]);
            }
        }
        #pragma unroll
        for (int r = 0; r < 2; r++)
        #pragma unroll
        for (int c = 0; c < 2; c++)
        #pragma unroll
        for (int q = 0; q < 4; q++) {
            int ec = ed[r][c][q] < 0 ? 0 : ed[r][c][q];
            sel[r][c][q] = (ec == t) ? acc[r][c][q] : sel[r][c][q];
        }
        if (t < 7) {
            #pragma unroll
            for (int i = 0; i < 2; i++) {
                int idx = tid + i * 512;
                int row = idx >> 4, ch = idx & 15;
                int boff = (row * 256 + ch * 16) ^ ((row & 7) << 4);
                *(uint4*)((char*)AH[cur ^ 1] + boff) = nh[i];
                *(uint4*)((char*)AL[cur ^ 1] + boff) = nl[i];
            }
        }
        __syncthreads();
    }
    #pragma unroll
    for (int r = 0; r < 2; r++)
    #pragma unroll
    for (int c = 0; c < 2; c++)
    #pragma unroll
    for (int q = 0; q < 4; q++) {
        float v = (ed[r][c][q] == -1) ? -1e10f : sel[r][c][q];
        v = (v >= 0.f) ? v : 0.2f * v;
        size_t n = n0 + wr + r * 16 + 4 * lg + q;
        size_t m = m0 + wc + c * 16 + lr;
        att[((size_t)b * 512 + n) * 512 + m] = v;
    }
}

// ---------------------------------------------------------------------------
// out v2: fused softmax + (att @ VP) + Pb. att row-slice kept in registers
// (single global read). Row max/sum via 8-lane shfl groups.
// ---------------------------------------------------------------------------
__launch_bounds__(256, 2)
__global__ void out_kernel(const float* __restrict__ att,
                           const u16* __restrict__ VTH, const u16* __restrict__ VTL,
                           const float* __restrict__ Pb, float* __restrict__ out) {
    const int id = blockIdx.x;
    const int xcd = id & 7, j = id >> 3;
    const int b = xcd * 4 + (j >> 4);
    const int n0 = (j & 15) * 32;
    __shared__ u16 PH[32 * 64], PL[32 * 64];
    __shared__ u16 VH[128 * 64], VL[128 * 64];
    const int tid = threadIdx.x;
    const int row = tid >> 3, c8 = tid & 7;
    // load this thread's att slice: row n0+row, cols {mc*64 + c8*8 .. +8}
    float4 av0[8], av1[8];
    const float4* rp = (const float4*)(att + ((size_t)b * 512 + n0 + row) * 512);
    #pragma unroll
    for (int mc = 0; mc < 8; mc++) {
        av0[mc] = rp[mc * 16 + c8 * 2];
        av1[mc] = rp[mc * 16 + c8 * 2 + 1];
    }
    float mx = -1e30f;
    #pragma unroll
    for (int mc = 0; mc < 8; mc++) {
        mx = fmaxf(mx, fmaxf(fmaxf(fmaxf(av0[mc].x, av0[mc].y), fmaxf(av0[mc].z, av0[mc].w)),
                             fmaxf(fmaxf(av1[mc].x, av1[mc].y), fmaxf(av1[mc].z, av1[mc].w))));
    }
    #pragma unroll
    for (int o = 1; o < 8; o <<= 1) mx = fmaxf(mx, __shfl_xor(mx, o, 64));
    float s = 0.f;
    #pragma unroll
    for (int mc = 0; mc < 8; mc++) {
        av0[mc].x = expf(av0[mc].x - mx); av0[mc].y = expf(av0[mc].y - mx);
        av0[mc].z = expf(av0[mc].z - mx); av0[mc].w = expf(av0[mc].w - mx);
        av1[mc].x = expf(av1[mc].x - mx); av1[mc].y = expf(av1[mc].y - mx);
        av1[mc].z = expf(av1[mc].z - mx); av1[mc].w = expf(av1[mc].w - mx);
        s += av0[mc].x + av0[mc].y + av0[mc].z + av0[mc].w
           + av1[mc].x + av1[mc].y + av1[mc].z + av1[mc].w;
    }
    #pragma unroll
    for (int o = 1; o < 8; o <<= 1) s += __shfl_xor(s, o, 64);
    const float inv = 1.0f / s;
    const int wid = tid >> 6, lane = tid & 63;
    const int lr = lane & 15, lg = lane >> 4;
    const int wc = wid * 32;
    f32x4 acc[2][2] = {};
    for (int mc = 0; mc < 8; mc++) {
        {   // stage P chunk from registers (normalize + hilo split)
            union { u16 us[8]; uint4 v; } uh, ul;
            float xs0 = av0[mc].x * inv, xs1 = av0[mc].y * inv;
            float xs2 = av0[mc].z * inv, xs3 = av0[mc].w * inv;
            float xs4 = av1[mc].x * inv, xs5 = av1[mc].y * inv;
            float xs6 = av1[mc].z * inv, xs7 = av1[mc].w * inv;
            split_hl(xs0, uh.us[0], ul.us[0]); split_hl(xs1, uh.us[1], ul.us[1]);
            split_hl(xs2, uh.us[2], ul.us[2]); split_hl(xs3, uh.us[3], ul.us[3]);
            split_hl(xs4, uh.us[4], ul.us[4]); split_hl(xs5, uh.us[5], ul.us[5]);
            split_hl(xs6, uh.us[6], ul.us[6]); split_hl(xs7, uh.us[7], ul.us[7]);
            int boff = (row * 128 + c8 * 16) ^ ((row & 7) << 4);
            *(uint4*)((char*)PH + boff) = uh.v;
            *(uint4*)((char*)PL + boff) = ul.v;
        }
        #pragma unroll
        for (int i = 0; i < 4; i++) {   // stage V chunk (128 d x 64 m)
            int idx = tid + i * 256;
            int vrow = idx >> 3, ch = idx & 7;
            size_t src = ((size_t)(b * 128 + vrow)) * 512 + mc * 64;
            int boff = (vrow * 128 + ch * 16) ^ ((vrow & 7) << 4);
            *(uint4*)((char*)VH + boff) = ((const uint4*)(VTH + src))[ch];
            *(uint4*)((char*)VL + boff) = ((const uint4*)(VTL + src))[ch];
        }
        __syncthreads();
        #pragma unroll
        for (int ks = 0; ks < 2; ks++) {
            const int kb2 = (ks * 32 + lg * 8) * 2;
            bf16x8 ah[2], al[2];
            #pragma unroll
            for (int r = 0; r < 2; r++) {
                int prow = r * 16 + lr;
                int boff = (prow * 128 + kb2) ^ ((prow & 7) << 4);
                ah[r] = *(const bf16x8*)((const char*)PH + boff);
                al[r] = *(const bf16x8*)((const char*)PL + boff);
            }
            #pragma unroll
            for (int c = 0; c < 2; c++) {
                int vrow = wc + c * 16 + lr;
                int boff = (vrow * 128 + kb2) ^ ((vrow & 7) << 4);
                bf16x8 bh = *(const bf16x8*)((const char*)VH + boff);
                bf16x8 bl = *(const bf16x8*)((const char*)VL + boff);
                #pragma unroll
                for (int r = 0; r < 2; r++) {
                    acc[r][c] = mfma16(ah[r], bh, acc[r][c]);
                    acc[r][c] = mfma16(ah[r], bl, acc[r][c]);
                    acc[r][c] = mfma16(al[r], bh, acc[r][c]);
                }
            }
        }
        __syncthreads();
    }
    #pragma unroll
    for (int r = 0; r < 2; r++)
    #pragma unroll
    for (int c = 0; c < 2; c++)
    #pragma unroll
    for (int q = 0; q < 4; q++) {
        int n = n0 + r * 16 + 4 * lg + q;
        int d = wc + c * 16 + lr;
        out[((size_t)b * 512 + n) * 128 + d] = acc[r][c][q] + Pb[d];
    }
}

extern "C" void kernel_launch(void* const* d_in, const int* in_sizes, int n_in,
                              void* d_out, int out_size, void* d_ws, size_t ws_size,
                              hipStream_t stream) {
    (void)in_sizes; (void)n_in; (void)out_size; (void)ws_size;
    const float* X  = (const float*)d_in[0];
    const void*  E  = d_in[1];
    const float* Qw = (const float*)d_in[2];
    const float* Qb = (const float*)d_in[3];
    const float* Kw = (const float*)d_in[4];
    const float* Kb = (const float*)d_in[5];
    const float* Vw = (const float*)d_in[6];
    const float* Vb = (const float*)d_in[7];
    const float* Aa = (const float*)d_in[8];
    const float* Pw = (const float*)d_in[9];
    const float* Pb = (const float*)d_in[10];
    float* out = (float*)d_out;

    char* ws = (char*)d_ws;
    size_t cur = 0;
    auto alloc = [&](size_t bytes) -> char* {
        char* p = ws + cur;
        cur += (bytes + 255) & ~(size_t)255;
        return p;
    };
    int*   flag = (int*)  alloc(4);
    u16*   WH   = (u16*)  alloc((size_t)1280 * 128 * 2);
    u16*   WL   = (u16*)  alloc((size_t)1280 * 128 * 2);
    float* bcat = (float*)alloc(1280 * 4);
    u16*   CH   = (u16*)  alloc((size_t)16384 * 1280 * 2);
    u16*   CL   = (u16*)  alloc((size_t)16384 * 1280 * 2);
    u16*   VTH  = (u16*)  alloc((size_t)32 * 128 * 512 * 2);
    u16*   VTL  = (u16*)  alloc((size_t)32 * 128 * 512 * 2);
    float* att  = (float*)alloc((size_t)32 * 512 * 512 * 4);
    signed char* E8 = (signed char*)alloc((size_t)32 * 512 * 512);

    prep_kernel<<<640, 256, 0, stream>>>(Qw, Qb, Kw, Kb, Vw, Vb, Aa, Pw, WH, WL, bcat);
    detect_kernel<<<1, 256, 0, stream>>>((const int*)E, flag);
    econv_kernel<<<8192, 256, 0, stream>>>(E, flag, E8);
    gemm1_kernel<<<512, 256, 0, stream>>>(X, WH, WL, bcat, CH, CL, VTH, VTL);
    scores_kernel<<<1024, 512, 0, stream>>>(CH, CL, E8, att);
    out_kernel<<<512, 256, 0, stream>>>(att, VTH, VTL, Pb, out);
}